// Round 8
// baseline (179.531 us; speedup 1.0000x reference)
//
#include <hip/hip_runtime.h>

#define NROWS 8192
#define HALF  4096
#define DIM   256
#define JS    16                 // j-splits across grid
#define JRANGE 512               // columns per block
#define JTILES 32                // 16-row j-tiles per block
#define IPB   256                // i rows per block
#define IPW   64                 // i rows per wave

typedef short bf16x8 __attribute__((ext_vector_type(8)));
typedef float f32x4  __attribute__((ext_vector_type(4)));

// async global->LDS, 16B per lane; LDS dest = wave-uniform base + lane*16
#define GLOAD16(g, l) __builtin_amdgcn_global_load_lds( \
    (const __attribute__((address_space(1))) unsigned int*)(g), \
    (__attribute__((address_space(3))) unsigned int*)(l), 16, 0, 0)

__device__ __forceinline__ unsigned short f2bf(float f) {
    unsigned int u = __float_as_uint(f);
    u += 0x7FFFu + ((u >> 16) & 1u);          // round-to-nearest-even
    return (unsigned short)(u >> 16);
}

// --- prep: zb = bf16(sqrt(2)*z) (MFMA then yields sim units directly),
//     exact fp32 positive dots, finish-counter = 0 ---
__global__ void k_prep(const float* __restrict__ z1, const float* __restrict__ z2,
                       unsigned short* __restrict__ zb, float* __restrict__ pos,
                       unsigned* __restrict__ cnt) {
    if (blockIdx.x == 0 && threadIdx.x == 0) *cnt = 0u;
    const float R2 = 1.41421356237309515f;     // sqrt(2): (R2*z)·(R2*z) = 2*z·z = sim
    int w = threadIdx.x >> 6, lane = threadIdx.x & 63;
    int row = blockIdx.x * 4 + w;              // 0 .. 4095
    float4 a = *(const float4*)(z1 + (size_t)row * DIM + lane * 4);
    float4 b = *(const float4*)(z2 + (size_t)row * DIM + lane * 4);

    uint2 pa, pb;
    pa.x = (unsigned int)f2bf(a.x*R2) | ((unsigned int)f2bf(a.y*R2) << 16);
    pa.y = (unsigned int)f2bf(a.z*R2) | ((unsigned int)f2bf(a.w*R2) << 16);
    pb.x = (unsigned int)f2bf(b.x*R2) | ((unsigned int)f2bf(b.y*R2) << 16);
    pb.y = (unsigned int)f2bf(b.z*R2) | ((unsigned int)f2bf(b.w*R2) << 16);
    *(uint2*)(zb + (size_t)row * DIM + lane * 4)          = pa;
    *(uint2*)(zb + (size_t)(row + HALF) * DIM + lane * 4) = pb;

    float d = a.x * b.x + a.y * b.y + a.z * b.z + a.w * b.w;
    #pragma unroll
    for (int k = 32; k; k >>= 1) d += __shfl_xor(d, k);
    if (lane == 0) pos[row] = 2.0f * d;        // exact fp32, sim units
}

// ---------------- main: MFMA matmul + online LSE + fused finish ----------------
__global__ __launch_bounds__(256, 2)
void k_main(const unsigned short* __restrict__ zb, float2* __restrict__ part,
            const float* __restrict__ pos, unsigned* __restrict__ cnt,
            float* __restrict__ out) {
    __shared__ __align__(16) char lds[4][8192];  // 4 static 16-row buffers
    char* ldsflat = &lds[0][0];

    const int tid  = threadIdx.x;
    const int w    = tid >> 6;
    const int lane = tid & 63;
    const int col  = lane & 15;        // i-local (C column)
    const int kg   = lane >> 4;        // k-group / j-subrow group
    const int ib   = blockIdx.x & 31;  // 32 i-tiles
    const int js   = blockIdx.x >> 5;  // 16 j-splits
    const int iw   = ib * IPB + w * IPW;
    const int jb0  = js * JRANGE;
    const int swz  = (lane & 7) << 4;  // read-side XOR key ((row&7)<<4), row=col
    const int dr   = col - kg * 4;     // acc reg index hitting the diagonal

    const char* zbb = (const char*)zb;

    // pre-swizzled global source offsets (involution of the LDS XOR swizzle)
    const int jp0 = w * 1024 + lane * 16;          // chunk 0 phys
    const int jp1 = 4096 + jp0;                    // chunk 1 phys
    const int jg0 = jp0 ^ (((jp0 >> 9) & 7) << 4);
    const int jg1 = jp1 ^ (((jp1 >> 9) & 7) << 4);

    // ---- i-panel prologue: global -> LDS (async, pre-swizzled) -> registers ----
    bf16x8 bf[4][8];
    {
        int igo[4];
        #pragma unroll
        for (int k = 0; k < 4; ++k) {
            int p = k * 4096 + w * 1024 + lane * 16;
            igo[k] = p ^ (((p >> 9) & 7) << 4);
        }
        #pragma unroll
        for (int p = 0; p < 8; ++p) {              // pass p: rows [32p, 32p+32)
            const char* gib = zbb + (size_t)(ib * IPB + p * 32) * 512;
            #pragma unroll
            for (int k = 0; k < 4; ++k)
                GLOAD16(gib + igo[k], ldsflat + k * 4096 + w * 1024);
            __syncthreads();                        // drains vmcnt -> data in LDS
            if ((p >> 1) == w) {                    // wave w owns passes 2w, 2w+1
                #pragma unroll
                for (int h = 0; h < 2; ++h) {
                    const char* tb = ldsflat + h * 8192;
                    #pragma unroll
                    for (int kk = 0; kk < 8; ++kk)
                        bf[(p & 1) * 2 + h][kk] =
                            *(const bf16x8*)(tb + col * 512 + (((kk << 6) | (kg << 4)) ^ swz));
                }
            }
            __syncthreads();
        }
    }

    float m[4], l[4];
    #pragma unroll
    for (int is = 0; is < 4; ++is) { m[is] = -1e30f; l[is] = 0.0f; }

    // static af addressing: one base + per-kk lane consts + buffer imm offsets
    const char* ap = ldsflat + col * 512;
    int aoff[8];
    #pragma unroll
    for (int kk = 0; kk < 8; ++kk) aoff[kk] = ((kk << 6) | (kg << 4)) ^ swz;

    const int dt = (iw - jb0) >> 4;                // tile idx of diagonal for is=0
    const char* jbase = zbb + (size_t)jb0 * 512;

#define JSTAGE(T, B) do { \
    GLOAD16(jbase + (size_t)(T) * 8192 + jg0, ldsflat + (B) * 8192 + w * 1024); \
    GLOAD16(jbase + (size_t)(T) * 8192 + jg1, ldsflat + (B) * 8192 + 4096 + w * 1024); \
} while (0)

#define MASKD(X) do { \
    _Pragma("unroll") \
    for (int r = 0; r < 4; ++r) if (dr == r) X[r] = -1e30f; \
} while (0)

#define LSE_UPD(X, is_) do { \
    float t0 = fmaxf(fmaxf(X[0], X[1]), fmaxf(X[2], X[3])); \
    float mn = fmaxf(m[is_], t0); \
    float rs = __expf(m[is_] - mn); \
    float e0 = __expf(X[0] - mn), e1 = __expf(X[1] - mn); \
    float e2 = __expf(X[2] - mn), e3 = __expf(X[3] - mn); \
    l[is_] = fmaf(l[is_], rs, (e0 + e1) + (e2 + e3)); \
    m[is_] = mn; \
} while (0)

// k-major MFMA order, 4 independent accumulator chains, single straight-line BB
// (round-6 lesson: is-major order + epilogue branches split BBs -> scheduler
//  could not pack the serial 8-MFMA chains -> MfmaUtil stuck at 29%)
#define COMPUTE_TILE(B, T) do { \
    bf16x8 af[8]; \
    _Pragma("unroll") \
    for (int kk = 0; kk < 8; ++kk) \
        af[kk] = *(const bf16x8*)(ap + aoff[kk] + (B) * 8192); \
    f32x4 a0 = {0.f, 0.f, 0.f, 0.f}; \
    f32x4 a1 = a0, a2 = a0, a3 = a0; \
    _Pragma("unroll") \
    for (int kk = 0; kk < 8; ++kk) { \
        a0 = __builtin_amdgcn_mfma_f32_16x16x32_bf16(af[kk], bf[0][kk], a0, 0, 0, 0); \
        a1 = __builtin_amdgcn_mfma_f32_16x16x32_bf16(af[kk], bf[1][kk], a1, 0, 0, 0); \
        a2 = __builtin_amdgcn_mfma_f32_16x16x32_bf16(af[kk], bf[2][kk], a2, 0, 0, 0); \
        a3 = __builtin_amdgcn_mfma_f32_16x16x32_bf16(af[kk], bf[3][kk], a3, 0, 0, 0); \
    } \
    const int dd = (T) - dt; \
    if (dd == 0) MASKD(a0); \
    if (dd == 1) MASKD(a1); \
    if (dd == 2) MASKD(a2); \
    if (dd == 3) MASKD(a3); \
    LSE_UPD(a0, 0); \
    LSE_UPD(a1, 1); \
    LSE_UPD(a2, 2); \
    LSE_UPD(a3, 3); \
} while (0)

    // prologue: tiles 0,1 -> L0,L1
    JSTAGE(0, 0); JSTAGE(1, 1);
    __syncthreads();

    for (int u = 0; u < 8; ++u) {
        const int t = u * 4;
        // half A: stage t+2,t+3 -> L2,L3 ; compute t (L0), t+1 (L1)
        JSTAGE(t + 2, 2); JSTAGE(t + 3, 3);
        COMPUTE_TILE(0, t);
        COMPUTE_TILE(1, t + 1);
        __syncthreads();
        // half B: stage t+4,t+5 -> L0,L1 ; compute t+2 (L2), t+3 (L3)
        if (u < 7) { JSTAGE(t + 4, 0); JSTAGE(t + 5, 1); }
        COMPUTE_TILE(2, t + 2);
        COMPUTE_TILE(3, t + 3);
        __syncthreads();
    }

    // combine the 4 kg groups holding the same i
    #pragma unroll
    for (int is = 0; is < 4; ++is) {
        float mm = m[is], ll = l[is];
        #pragma unroll
        for (int msk = 16; msk <= 32; msk <<= 1) {
            float mo  = __shfl_xor(mm, msk);
            float lo_ = __shfl_xor(ll, msk);
            float mn  = fmaxf(mm, mo);
            ll = ll * __expf(mm - mn) + lo_ * __expf(mo - mn);
            mm = mn;
        }
        if (kg == 0) {
            int i = iw + is * 16 + col;
            part[i * JS + js] = make_float2(mm, ll);
        }
    }
#undef JSTAGE
#undef MASKD
#undef LSE_UPD
#undef COMPUTE_TILE

    // ---- fused finish: last block to arrive merges partials -> loss ----
    __threadfence();                                // release part[] writes
    __shared__ unsigned tok;
    if (tid == 0) tok = atomicAdd(cnt, 1u);
    __syncthreads();
    if (tok == (unsigned)(gridDim.x - 1)) {
        __threadfence();                            // acquire all blocks' part[]
        float accl = 0.0f;
        for (int rr = 0; rr < 32; ++rr) {
            int i = rr * 256 + tid;
            const float2* p = part + (size_t)i * JS;
            float2 v[JS];
            float M = -3e30f;
            #pragma unroll
            for (int s = 0; s < JS; ++s) { v[s] = p[s]; M = fmaxf(M, v[s].x); }
            float L = 0.0f;
            #pragma unroll
            for (int s = 0; s < JS; ++s) L += v[s].y * __expf(v[s].x - M);
            accl += M + __logf(L) - pos[i & (HALF - 1)];
        }
        #pragma unroll
        for (int k = 32; k; k >>= 1) accl += __shfl_down(accl, k);
        float* ps = (float*)ldsflat;
        if ((tid & 63) == 0) ps[tid >> 6] = accl;
        __syncthreads();
        if (tid == 0) *out = (ps[0] + ps[1] + ps[2] + ps[3]) * (1.0f / (float)NROWS);
    }
}

extern "C" void kernel_launch(void* const* d_in, const int* in_sizes, int n_in,
                              void* d_out, int out_size, void* d_ws, size_t ws_size,
                              hipStream_t stream) {
    const float* z1 = (const float*)d_in[0];
    const float* z2 = (const float*)d_in[1];
    float* out = (float*)d_out;

    char* ws = (char*)d_ws;
    unsigned short* zb = (unsigned short*)ws;                          // 4 MiB
    float* pos   = (float*)(ws + 4u * 1024u * 1024u);                  // 16 KiB
    unsigned* cnt = (unsigned*)(ws + 4u * 1024u * 1024u + 32768u);     // 4 B (in pad)
    float2* part = (float2*)(ws + 4u * 1024u * 1024u + 65536u);        // 1 MiB

    k_prep <<<1024, 256, 0, stream>>>(z1, z2, zb, pos, cnt);
    k_main <<<512,  256, 0, stream>>>(zb, part, pos, cnt, out);
}

// Round 9
// 100.600 us; speedup vs baseline: 1.7846x; 1.7846x over previous
//
#include <hip/hip_runtime.h>

#define NROWS 8192
#define HALF  4096
#define DIM   256
#define JS    16                 // j-splits across grid
#define JRANGE 512               // columns per block
#define JTILES 32                // 16-row j-tiles per block
#define IPB   128                // i rows per block (4 waves x 32)
#define IPW   32                 // i rows per wave

typedef short bf16x8 __attribute__((ext_vector_type(8)));
typedef float f32x4  __attribute__((ext_vector_type(4)));

// async global->LDS, 16B per lane; LDS dest = wave-uniform base + lane*16
#define GLOAD16(g, l) __builtin_amdgcn_global_load_lds( \
    (const __attribute__((address_space(1))) unsigned int*)(g), \
    (__attribute__((address_space(3))) unsigned int*)(l), 16, 0, 0)

__device__ __forceinline__ unsigned short f2bf(float f) {
    unsigned int u = __float_as_uint(f);
    u += 0x7FFFu + ((u >> 16) & 1u);          // round-to-nearest-even
    return (unsigned short)(u >> 16);
}

// --- prep: zb = bf16(sqrt(2)*z) (MFMA then yields sim units directly),
//     exact fp32 positive dots, out = 0 ---
__global__ void k_prep(const float* __restrict__ z1, const float* __restrict__ z2,
                       unsigned short* __restrict__ zb, float* __restrict__ pos,
                       float* __restrict__ out) {
    if (blockIdx.x == 0 && threadIdx.x == 0) *out = 0.0f;
    const float R2 = 1.41421356237309515f;     // sqrt(2): (R2*z)·(R2*z) = 2*z·z = sim
    int w = threadIdx.x >> 6, lane = threadIdx.x & 63;
    int row = blockIdx.x * 4 + w;              // 0 .. 4095
    float4 a = *(const float4*)(z1 + (size_t)row * DIM + lane * 4);
    float4 b = *(const float4*)(z2 + (size_t)row * DIM + lane * 4);

    uint2 pa, pb;
    pa.x = (unsigned int)f2bf(a.x*R2) | ((unsigned int)f2bf(a.y*R2) << 16);
    pa.y = (unsigned int)f2bf(a.z*R2) | ((unsigned int)f2bf(a.w*R2) << 16);
    pb.x = (unsigned int)f2bf(b.x*R2) | ((unsigned int)f2bf(b.y*R2) << 16);
    pb.y = (unsigned int)f2bf(b.z*R2) | ((unsigned int)f2bf(b.w*R2) << 16);
    *(uint2*)(zb + (size_t)row * DIM + lane * 4)          = pa;
    *(uint2*)(zb + (size_t)(row + HALF) * DIM + lane * 4) = pb;

    float d = a.x * b.x + a.y * b.y + a.z * b.z + a.w * b.w;
    #pragma unroll
    for (int k = 32; k; k >>= 1) d += __shfl_xor(d, k);
    if (lane == 0) pos[row] = 2.0f * d;        // exact fp32, sim units
}

// ---------------- main: MFMA matmul + online LSE ----------------
// Round-8 lesson: 4-chain k-major spilled (WRITE_SIZE 3.8MB). Round-6 lesson:
// 2 waves/SIMD can't hide latency (no pipe >45%). Fix: occupancy. IPW=32 ->
// bf[2][8]=64 VGPRs, grid 1024 = 4 blocks/CU = 4 waves/SIMD, cap 128 regs.
__global__ __launch_bounds__(256, 4)
void k_main(const unsigned short* __restrict__ zb, float2* __restrict__ part) {
    __shared__ __align__(16) char lds[4][8192];  // 4 static 16-row buffers
    char* ldsflat = &lds[0][0];

    const int tid  = threadIdx.x;
    const int w    = tid >> 6;
    const int lane = tid & 63;
    const int col  = lane & 15;        // i-local (C column)
    const int kg   = lane >> 4;        // k-group / j-subrow group
    const int ib   = blockIdx.x & 63;  // 64 i-tiles
    const int js   = blockIdx.x >> 6;  // 16 j-splits
    const int iw   = ib * IPB + w * IPW;
    const int jb0  = js * JRANGE;
    const int swz  = (lane & 7) << 4;  // read-side XOR key ((row&7)<<4), row=col
    const int dr   = col - kg * 4;     // acc reg index hitting the diagonal

    const char* zbb = (const char*)zb;

    // pre-swizzled global source offsets (involution of the LDS XOR swizzle)
    const int jp0 = w * 1024 + lane * 16;          // chunk 0 phys
    const int jp1 = 4096 + jp0;                    // chunk 1 phys
    const int jg0 = jp0 ^ (((jp0 >> 9) & 7) << 4);
    const int jg1 = jp1 ^ (((jp1 >> 9) & 7) << 4);

    // ---- i-panel prologue: global -> LDS (async, pre-swizzled) -> registers ----
    bf16x8 bf[2][8];                   // wave's 32 i-rows, 64 VGPRs
    {
        int igo[4];
        #pragma unroll
        for (int k = 0; k < 4; ++k) {
            int p = k * 4096 + w * 1024 + lane * 16;
            igo[k] = p ^ (((p >> 9) & 7) << 4);
        }
        #pragma unroll
        for (int q = 0; q < 4; ++q) {             // pass q: rows [32q, 32q+32)
            const char* gib = zbb + (size_t)(ib * IPB + q * 32) * 512;
            #pragma unroll
            for (int k = 0; k < 4; ++k)
                GLOAD16(gib + igo[k], ldsflat + k * 4096 + w * 1024);
            __syncthreads();                      // drains vmcnt -> data in LDS
            if (q == w) {                         // wave w owns pass w
                #pragma unroll
                for (int h = 0; h < 2; ++h) {
                    const char* tb = ldsflat + h * 8192;
                    #pragma unroll
                    for (int kk = 0; kk < 8; ++kk)
                        bf[h][kk] =
                            *(const bf16x8*)(tb + col * 512 + (((kk << 6) | (kg << 4)) ^ swz));
                }
            }
            __syncthreads();
        }
    }

    float m[2], l[2];
    m[0] = m[1] = -1e30f;
    l[0] = l[1] = 0.0f;

    // static af addressing: one base + per-kk lane consts + buffer imm offsets
    const char* ap = ldsflat + col * 512;
    int aoff[8];
    #pragma unroll
    for (int kk = 0; kk < 8; ++kk) aoff[kk] = ((kk << 6) | (kg << 4)) ^ swz;

    const int dt = (iw - jb0) >> 4;                // tile idx of diagonal for is=0
    const char* jbase = zbb + (size_t)jb0 * 512;

#define JSTAGE(T, B) do { \
    GLOAD16(jbase + (size_t)(T) * 8192 + jg0, ldsflat + (B) * 8192 + w * 1024); \
    GLOAD16(jbase + (size_t)(T) * 8192 + jg1, ldsflat + (B) * 8192 + 4096 + w * 1024); \
} while (0)

#define MASKD(X) do { \
    _Pragma("unroll") \
    for (int r = 0; r < 4; ++r) if (dr == r) X[r] = -1e30f; \
} while (0)

#define LSE_UPD(X, is_) do { \
    float t0 = fmaxf(fmaxf(X[0], X[1]), fmaxf(X[2], X[3])); \
    if (__any(t0 > m[is_])) { \
        float mn = fmaxf(m[is_], t0); \
        l[is_] *= __expf(m[is_] - mn); \
        m[is_] = mn; \
    } \
    l[is_] += __expf(X[0] - m[is_]) + __expf(X[1] - m[is_]) \
            + __expf(X[2] - m[is_]) + __expf(X[3] - m[is_]); \
} while (0)

// 2 i-subtiles, af loaded in 4-reg halves (peak regs: 64 bf + 16 af + 8 acc)
#define COMPUTE_TILE(B, T) do { \
    f32x4 a0 = {0.f, 0.f, 0.f, 0.f}; \
    f32x4 a1 = a0; \
    bf16x8 af[4]; \
    _Pragma("unroll") \
    for (int kk = 0; kk < 4; ++kk) \
        af[kk] = *(const bf16x8*)(ap + aoff[kk] + (B) * 8192); \
    _Pragma("unroll") \
    for (int kk = 0; kk < 4; ++kk) { \
        a0 = __builtin_amdgcn_mfma_f32_16x16x32_bf16(af[kk], bf[0][kk], a0, 0, 0, 0); \
        a1 = __builtin_amdgcn_mfma_f32_16x16x32_bf16(af[kk], bf[1][kk], a1, 0, 0, 0); \
    } \
    _Pragma("unroll") \
    for (int kk = 0; kk < 4; ++kk) \
        af[kk] = *(const bf16x8*)(ap + aoff[kk + 4] + (B) * 8192); \
    _Pragma("unroll") \
    for (int kk = 0; kk < 4; ++kk) { \
        a0 = __builtin_amdgcn_mfma_f32_16x16x32_bf16(af[kk], bf[0][kk + 4], a0, 0, 0, 0); \
        a1 = __builtin_amdgcn_mfma_f32_16x16x32_bf16(af[kk], bf[1][kk + 4], a1, 0, 0, 0); \
    } \
    const int dd = (T) - dt; \
    if (dd == 0) MASKD(a0); \
    if (dd == 1) MASKD(a1); \
    LSE_UPD(a0, 0); \
    LSE_UPD(a1, 1); \
} while (0)

    // prologue: tiles 0,1 -> L0,L1
    JSTAGE(0, 0); JSTAGE(1, 1);
    __syncthreads();

    for (int u = 0; u < 8; ++u) {
        const int t = u * 4;
        // half A: stage t+2,t+3 -> L2,L3 ; compute t (L0), t+1 (L1)
        JSTAGE(t + 2, 2); JSTAGE(t + 3, 3);
        COMPUTE_TILE(0, t);
        COMPUTE_TILE(1, t + 1);
        __syncthreads();
        // half B: stage t+4,t+5 -> L0,L1 ; compute t+2 (L2), t+3 (L3)
        if (u < 7) { JSTAGE(t + 4, 0); JSTAGE(t + 5, 1); }
        COMPUTE_TILE(2, t + 2);
        COMPUTE_TILE(3, t + 3);
        __syncthreads();
    }

    // combine the 4 kg groups holding the same i
    #pragma unroll
    for (int is = 0; is < 2; ++is) {
        float mm = m[is], ll = l[is];
        #pragma unroll
        for (int msk = 16; msk <= 32; msk <<= 1) {
            float mo  = __shfl_xor(mm, msk);
            float lo_ = __shfl_xor(ll, msk);
            float mn  = fmaxf(mm, mo);
            ll = ll * __expf(mm - mn) + lo_ * __expf(mo - mn);
            mm = mn;
        }
        if (kg == 0) {
            int i = iw + is * 16 + col;
            part[i * JS + js] = make_float2(mm, ll);
        }
    }
#undef JSTAGE
#undef MASKD
#undef LSE_UPD
#undef COMPUTE_TILE
}

// ---------------- final: merge partials, loss, reduce ----------------
__global__ void k_final(const float2* __restrict__ part, const float* __restrict__ pos,
                        float* __restrict__ out) {
    int tid = threadIdx.x;
    int i = blockIdx.x * 256 + tid;
    const float2* p = part + (size_t)i * JS;
    float2 v[JS];
    float M = -3e30f;
    #pragma unroll
    for (int s = 0; s < JS; ++s) { v[s] = p[s]; M = fmaxf(M, v[s].x); }
    float L = 0.0f;
    #pragma unroll
    for (int s = 0; s < JS; ++s) L += v[s].y * __expf(v[s].x - M);
    float loss = M + __logf(L) - pos[i & (HALF - 1)];

    #pragma unroll
    for (int k = 32; k; k >>= 1) loss += __shfl_down(loss, k);
    __shared__ float ps[4];
    int w = tid >> 6, lane = tid & 63;
    if (lane == 0) ps[w] = loss;
    __syncthreads();
    if (tid == 0) atomicAdd(out, (ps[0] + ps[1] + ps[2] + ps[3]) * (1.0f / (float)NROWS));
}

extern "C" void kernel_launch(void* const* d_in, const int* in_sizes, int n_in,
                              void* d_out, int out_size, void* d_ws, size_t ws_size,
                              hipStream_t stream) {
    const float* z1 = (const float*)d_in[0];
    const float* z2 = (const float*)d_in[1];
    float* out = (float*)d_out;

    char* ws = (char*)d_ws;
    unsigned short* zb = (unsigned short*)ws;                          // 4 MiB
    float* pos  = (float*)(ws + 4u * 1024u * 1024u);                   // 16 KiB
    float2* part = (float2*)(ws + 4u * 1024u * 1024u + 65536u);        // 1 MiB

    k_prep <<<1024, 256, 0, stream>>>(z1, z2, zb, pos, out);
    k_main <<<1024, 256, 0, stream>>>(zb, part);
    k_final<<<32,   256, 0, stream>>>(part, pos, out);
}